// Round 14
// baseline (126.638 us; speedup 1.0000x reference)
//
#include <hip/hip_runtime.h>
#include <math.h>

#define BATCH 16384
#define EDIM 128
#define RD (EDIM * EDIM)      // 16384 floats = 64 KB
#define NREL 200
#define SPLIT 4
#define NBLK (NREL * SPLIT)   // 800
#define NTHR 256
#define QUARTER (BATCH / SPLIT)  // 4096
#define NJ (QUARTER / NTHR)      // 16
#define GE 16
#define LISTCAP 256

// ws layout (32-bit words):
//  [0 .. NBLK)  csum[] (float, per-block partials; plain stores)
//  [1024]       arrival counter (memset to 0 each launch)

__device__ __forceinline__ int load_idx(const void* p, int b, int is64) {
    if (is64) return (int)((const long long*)p)[b];
    return ((const int*)p)[b];
}

__global__ __launch_bounds__(NTHR) void rescal_kernel(
    const void* __restrict__ hI, const void* __restrict__ rI,
    const void* __restrict__ pI, const void* __restrict__ nI,
    const float* __restrict__ ent, const float* __restrict__ rel,
    float* __restrict__ ws, float* __restrict__ out) {
    const int t = threadIdx.x;
    const int bid0 = blockIdx.x;
    // rid-major XCD mapping (R13): all quarters of a relation on one XCD
    const int xcd = bid0 & 7;
    const int slot = bid0 >> 3;
    const int rid = xcd + 8 * (slot >> 2);
    const int qtr = slot & 3;
    const int lane = t & 63;
    const int wave = t >> 6;
    const int c2 = lane * 2;

    __shared__ float uw[4][GE][EDIM];   // 32 KB partial-u per wave
    __shared__ unsigned short list[LISTCAP];
    __shared__ unsigned int wtj[NJ][4];
    __shared__ unsigned int um4[4];
    __shared__ float wred[4], wsum[4];
    __shared__ int s_last;

    // ---- dtype detect ----
    unsigned int o = ((const unsigned int*)hI)[2 * t + 1] |
                     ((const unsigned int*)rI)[2 * t + 1] |
                     ((const unsigned int*)pI)[2 * t + 1] |
                     ((const unsigned int*)nI)[2 * t + 1];
#pragma unroll
    for (int off = 32; off; off >>= 1) o |= __shfl_xor(o, off, 64);
    if (lane == 0) um4[wave] = o;
    __syncthreads();
    const int is64 = ((um4[0] | um4[1] | um4[2] | um4[3]) == 0u) ? 1 : 0;

    // ---- coalesced ballot scan (R13, verbatim) ----
    const int qbase = qtr * QUARTER;
    unsigned long long bal[NJ];
#pragma unroll
    for (int j = 0; j < NJ; ++j) {
        const int rr = load_idx(rI, qbase + j * NTHR + t, is64);
        bal[j] = __ballot(rr == rid);
        if (lane == 0) wtj[j][wave] = (unsigned int)__popcll(bal[j]);
    }
    __syncthreads();
    int cnt;
    {
        unsigned int run = 0;
        const unsigned long long ltmask = (lane == 63) ? ~0ull >> 1
                                                       : (1ull << lane) - 1ull;
#pragma unroll
        for (int j = 0; j < NJ; ++j) {
            unsigned int wpre = 0, tj = 0;
#pragma unroll
            for (int w = 0; w < 4; ++w) {
                const unsigned int v = wtj[j][w];
                tj += v;
                wpre += (w < wave) ? v : 0;
            }
            if ((bal[j] >> lane) & 1ull) {
                const unsigned int rank =
                    run + wpre + (unsigned int)__popcll(bal[j] & ltmask);
                if (rank < LISTCAP) list[rank] = (unsigned short)(j * NTHR + t);
            }
            run += tj;
        }
        cnt = (int)run;
        if (cnt > LISTCAP) cnt = LISTCAP;
    }
    __syncthreads();

    const float* Rg = rel + (size_t)rid * RD;
    const int dlo = wave * 32;  // my d-range: [dlo, dlo+32)
    float lsum = 0.f;           // lane-0-of-wave meaningful
    float r2sum = 0.f;

    for (int g0 = 0; g0 < cnt; g0 += GE) {
        // ---- uniform element handles for this group ----
        int bidx[GE];
        const float* hrow[GE];
#pragma unroll
        for (int i = 0; i < GE; ++i) {
            int e = g0 + i;
            if (e >= cnt) e = cnt - 1;
            int b = qbase + (int)list[e];
            b = __builtin_amdgcn_readfirstlane(b);
            bidx[i] = b;
            int hix = load_idx(hI, b, is64);
            hix = __builtin_amdgcn_readfirstlane(hix);
            hrow[i] = ent + (size_t)hix * EDIM;
        }

        // ---- phase A: partial u over my 32 d's, all GE elements ----
        float2 acc[GE];
#pragma unroll
        for (int i = 0; i < GE; ++i) acc[i] = make_float2(0.f, 0.f);
        float r2p = 0.f;
#pragma unroll 4
        for (int db = 0; db < 16; ++db) {
            const int d0 = dlo + db * 2;
            const float2 ra = *(const float2*)(Rg + d0 * EDIM + c2);
            const float2 rb = *(const float2*)(Rg + (d0 + 1) * EDIM + c2);
            r2p = fmaf(ra.x, ra.x, fmaf(ra.y, ra.y, fmaf(rb.x, rb.x, fmaf(rb.y, rb.y, r2p))));
#pragma unroll
            for (int i = 0; i < GE; ++i) {
                const float2 hd = *(const float2*)(hrow[i] + d0);
                acc[i].x = fmaf(ra.x, hd.x, acc[i].x);
                acc[i].y = fmaf(ra.y, hd.x, acc[i].y);
                acc[i].x = fmaf(rb.x, hd.y, acc[i].x);
                acc[i].y = fmaf(rb.y, hd.y, acc[i].y);
            }
        }
#pragma unroll
        for (int i = 0; i < GE; ++i) *(float2*)&uw[wave][i][c2] = acc[i];
        if (g0 == 0) {
#pragma unroll
            for (int off = 32; off; off >>= 1) r2p += __shfl_xor(r2p, off, 64);
            if (lane == 0) wred[wave] = r2p;
        }
        __syncthreads();
        if (g0 == 0) r2sum = wred[0] + wred[1] + wred[2] + wred[3];

        // ---- phase B: wave handles elements wave*4 .. wave*4+3 ----
#pragma unroll
        for (int q = 0; q < 4; ++q) {
            const int i = wave * 4 + q;
            const float2 v0 = *(const float2*)&uw[0][i][c2];
            const float2 v1 = *(const float2*)&uw[1][i][c2];
            const float2 v2 = *(const float2*)&uw[2][i][c2];
            const float2 v3 = *(const float2*)&uw[3][i][c2];
            const float ux = v0.x + v1.x + v2.x + v3.x;
            const float uy = v0.y + v1.y + v2.y + v3.y;
            const int b = bidx[i];
            const int pi = __builtin_amdgcn_readfirstlane(load_idx(pI, b, is64));
            const int ni = __builtin_amdgcn_readfirstlane(load_idx(nI, b, is64));
            const float2 hv2 = *(const float2*)(hrow[i] + c2);
            const float2 tp2 = *(const float2*)(ent + (size_t)pi * EDIM + c2);
            const float2 tn2 = *(const float2*)(ent + (size_t)ni * EDIM + c2);
            float dp = ux * tp2.x + uy * tp2.y;
            float dn = ux * tn2.x + uy * tn2.y;
            float e2 = hv2.x * hv2.x + hv2.y * hv2.y + tp2.x * tp2.x + tp2.y * tp2.y +
                       tn2.x * tn2.x + tn2.y * tn2.y;
#pragma unroll
            for (int off = 32; off; off >>= 1) {
                dp += __shfl_xor(dp, off, 64);
                dn += __shfl_xor(dn, off, 64);
                e2 += __shfl_xor(e2, off, 64);
            }
            if (lane == 0 && (g0 + i) < cnt) {
                const float x = dn - dp;  // neg_score - pos_score
                const float spl = (x > 0.f) ? (x + log1pf(expf(-x))) : log1pf(expf(x));
                lsum += spl + 1e-5f * 0.5f * (e2 + r2sum);
            }
        }
        __syncthreads();  // uw reusable next group
    }

    // ---- epilogue: block partial + last-block final reduction ----
    if (lane == 0) wsum[wave] = lsum;
    __syncthreads();
    if (t == 0) {
        ws[bid0] = wsum[0] + wsum[1] + wsum[2] + wsum[3];
        __threadfence();
        unsigned int old = atomicAdd((unsigned int*)(ws + 1024), 1u);
        s_last = (old == (unsigned int)(NBLK - 1)) ? 1 : 0;
    }
    __syncthreads();
    if (s_last) {
        __threadfence();
        float a = 0.f;
        for (int i = t; i < NBLK; i += NTHR)
            a += __hip_atomic_load(&ws[i], __ATOMIC_ACQUIRE, __HIP_MEMORY_SCOPE_AGENT);
#pragma unroll
        for (int off = 32; off; off >>= 1) a += __shfl_down(a, off, 64);
        if (lane == 0) wsum[wave] = a;
        __syncthreads();
        if (t == 0)
            out[0] = (wsum[0] + wsum[1] + wsum[2] + wsum[3]) * (1.0f / (float)BATCH);
    }
}

extern "C" void kernel_launch(void* const* d_in, const int* in_sizes, int n_in,
                              void* d_out, int out_size, void* d_ws, size_t ws_size,
                              hipStream_t stream) {
    const void* h = d_in[0];
    const void* r = d_in[1];
    const void* pt = d_in[2];
    const void* nt = d_in[3];
    const float* ent = (const float*)d_in[4];
    const float* rel = (const float*)d_in[5];

    // zero the arrival counter (ws word 1024) — capture-legal memset node
    hipMemsetAsync((void*)((char*)d_ws + 1024 * sizeof(float)), 0,
                   sizeof(unsigned int), stream);
    rescal_kernel<<<NBLK, NTHR, 0, stream>>>(h, r, pt, nt, ent, rel,
                                             (float*)d_ws, (float*)d_out);
}

// Round 15
// 80.645 us; speedup vs baseline: 1.5703x; 1.5703x over previous
//
#include <hip/hip_runtime.h>
#include <math.h>

#define BATCH 16384
#define EDIM 128
#define RD (EDIM * EDIM)      // 16384 floats = 64 KB
#define NREL 200
#define SPLIT 8
#define NBLK (NREL * SPLIT)   // 1600
#define NTHR 256
#define PIECE (BATCH / SPLIT) // 2048
#define NJ (PIECE / NTHR)     // 8
#define EB 4
#define LISTCAP 128

// ws layout (32-bit words):
//  [0 .. NBLK)  csum[] (float, per-block partials; plain stores)
//  [2048]       arrival counter (memset to 0 each launch)

__device__ __forceinline__ int load_idx(const void* p, int b, int is64) {
    if (is64) return (int)((const long long*)p)[b];
    return ((const int*)p)[b];
}

__global__ __launch_bounds__(NTHR) void rescal_kernel(
    const void* __restrict__ hI, const void* __restrict__ rI,
    const void* __restrict__ pI, const void* __restrict__ nI,
    const float* __restrict__ ent, const float* __restrict__ rel,
    float* __restrict__ ws, float* __restrict__ out) {
    const int t = threadIdx.x;
    const int bid0 = blockIdx.x;
    // rid-major XCD mapping: all 8 pieces of a relation land on XCD rid%8,
    // so its 64KB R row stays L2-resident (25 rids x 64KB = 1.6MB < 4MB L2).
    const int xcd = bid0 & 7;
    const int slot = bid0 >> 3;             // 0..199
    const int rid = xcd + 8 * (slot >> 3);  // 0..199
    const int piece = slot & 7;
    const int lane = t & 63;
    const int wave = t >> 6;
    const int c2 = lane * 2;

    __shared__ unsigned short list[LISTCAP];
    __shared__ unsigned int wtj[NJ][4];
    __shared__ unsigned int um4[4];
    __shared__ float wsum[4];
    __shared__ int s_last;

    // ---- dtype detect ----
    unsigned int o = ((const unsigned int*)hI)[2 * t + 1] |
                     ((const unsigned int*)rI)[2 * t + 1] |
                     ((const unsigned int*)pI)[2 * t + 1] |
                     ((const unsigned int*)nI)[2 * t + 1];
#pragma unroll
    for (int off = 32; off; off >>= 1) o |= __shfl_xor(o, off, 64);
    if (lane == 0) um4[wave] = o;
    __syncthreads();
    const int is64 = ((um4[0] | um4[1] | um4[2] | um4[3]) == 0u) ? 1 : 0;

    // ---- coalesced ballot scan of my piece ----
    const int qbase = piece * PIECE;
    unsigned long long bal[NJ];
#pragma unroll
    for (int j = 0; j < NJ; ++j) {
        const int rr = load_idx(rI, qbase + j * NTHR + t, is64);
        bal[j] = __ballot(rr == rid);
        if (lane == 0) wtj[j][wave] = (unsigned int)__popcll(bal[j]);
    }
    __syncthreads();
    int cnt;
    {
        unsigned int run = 0;
        const unsigned long long ltmask = (lane == 63) ? ~0ull >> 1
                                                       : (1ull << lane) - 1ull;
#pragma unroll
        for (int j = 0; j < NJ; ++j) {
            unsigned int wpre = 0, tj = 0;
#pragma unroll
            for (int w = 0; w < 4; ++w) {
                const unsigned int v = wtj[j][w];
                tj += v;
                wpre += (w < wave) ? v : 0;
            }
            if ((bal[j] >> lane) & 1ull) {
                const unsigned int rank =
                    run + wpre + (unsigned int)__popcll(bal[j] & ltmask);
                if (rank < LISTCAP) list[rank] = (unsigned short)(j * NTHR + t);
            }
            run += tj;
        }
        cnt = (int)run;
        if (cnt > LISTCAP) cnt = LISTCAP;
    }
    __syncthreads();  // list complete; no more block syncs until epilogue

    // ---- per-wave independent range ----
    const int per_wave = (cnt + 3) >> 2;
    int lo = wave * per_wave;
    int hi = (wave + 1) * per_wave;
    if (lo > cnt) lo = cnt;
    if (hi > cnt) hi = cnt;

    const float* Rg = rel + (size_t)rid * RD;
    float lsum = 0.f;  // lane-0-of-wave meaningful

    for (int e0 = lo; e0 < hi; e0 += EB) {
        // ---- uniform element handles ----
        int bidx[EB];
        const float* hrow[EB];
#pragma unroll
        for (int i = 0; i < EB; ++i) {
            int e = e0 + i;
            if (e >= hi) e = hi - 1;
            int b = qbase + (int)list[e];
            b = __builtin_amdgcn_readfirstlane(b);
            bidx[i] = b;
            int hix = load_idx(hI, b, is64);
            hix = __builtin_amdgcn_readfirstlane(hix);
            hrow[i] = ent + (size_t)hix * EDIM;
        }

        // ---- EARLY tail loads: issue HBM-miss entity rows before the R stream
        //      (vmcnt in-order drain completes them under the d-loop) ----
        float2 tpv[EB], tnv[EB], hvv[EB];
#pragma unroll
        for (int i = 0; i < EB; ++i) {
            const int b = bidx[i];
            const int pi = __builtin_amdgcn_readfirstlane(load_idx(pI, b, is64));
            const int ni = __builtin_amdgcn_readfirstlane(load_idx(nI, b, is64));
            tpv[i] = *(const float2*)(ent + (size_t)pi * EDIM + c2);
            tnv[i] = *(const float2*)(ent + (size_t)ni * EDIM + c2);
            hvv[i] = *(const float2*)(hrow[i] + c2);
        }

        // ---- d-loop: R streamed wave-wide, h via uniform scalar loads ----
        float2 acc[EB];
#pragma unroll
        for (int i = 0; i < EB; ++i) acc[i] = make_float2(0.f, 0.f);
        float r2p = 0.f;
#pragma unroll 4
        for (int db = 0; db < 32; ++db) {
            const float4 hv0 = *(const float4*)(hrow[0] + db * 4);
            const float4 hv1 = *(const float4*)(hrow[1] + db * 4);
            const float4 hv2 = *(const float4*)(hrow[2] + db * 4);
            const float4 hv3 = *(const float4*)(hrow[3] + db * 4);
#pragma unroll
            for (int jj = 0; jj < 4; ++jj) {
                const int d = db * 4 + jj;
                const float2 rv = *(const float2*)(Rg + d * EDIM + c2);
                r2p = fmaf(rv.x, rv.x, fmaf(rv.y, rv.y, r2p));
                const float h0 = (jj == 0) ? hv0.x : (jj == 1) ? hv0.y : (jj == 2) ? hv0.z : hv0.w;
                const float h1 = (jj == 0) ? hv1.x : (jj == 1) ? hv1.y : (jj == 2) ? hv1.z : hv1.w;
                const float h2 = (jj == 0) ? hv2.x : (jj == 1) ? hv2.y : (jj == 2) ? hv2.z : hv2.w;
                const float h3 = (jj == 0) ? hv3.x : (jj == 1) ? hv3.y : (jj == 2) ? hv3.z : hv3.w;
                acc[0].x = fmaf(rv.x, h0, acc[0].x); acc[0].y = fmaf(rv.y, h0, acc[0].y);
                acc[1].x = fmaf(rv.x, h1, acc[1].x); acc[1].y = fmaf(rv.y, h1, acc[1].y);
                acc[2].x = fmaf(rv.x, h2, acc[2].x); acc[2].y = fmaf(rv.y, h2, acc[2].y);
                acc[3].x = fmaf(rv.x, h3, acc[3].x); acc[3].y = fmaf(rv.y, h3, acc[3].y);
            }
        }
#pragma unroll
        for (int off = 32; off; off >>= 1) r2p += __shfl_xor(r2p, off, 64);
        const float r2w = r2p;

        // ---- tails: all operands already in registers ----
#pragma unroll
        for (int i = 0; i < EB; ++i) {
            float dp = acc[i].x * tpv[i].x + acc[i].y * tpv[i].y;
            float dn = acc[i].x * tnv[i].x + acc[i].y * tnv[i].y;
            float e2 = hvv[i].x * hvv[i].x + hvv[i].y * hvv[i].y +
                       tpv[i].x * tpv[i].x + tpv[i].y * tpv[i].y +
                       tnv[i].x * tnv[i].x + tnv[i].y * tnv[i].y;
#pragma unroll
            for (int off = 32; off; off >>= 1) {
                dp += __shfl_xor(dp, off, 64);
                dn += __shfl_xor(dn, off, 64);
                e2 += __shfl_xor(e2, off, 64);
            }
            if (lane == 0 && (e0 + i) < hi) {
                const float x = dn - dp;  // neg_score - pos_score
                const float spl = (x > 0.f) ? (x + log1pf(expf(-x))) : log1pf(expf(x));
                lsum += spl + 1e-5f * 0.5f * (e2 + r2w);
            }
        }
    }

    // ---- epilogue: block partial + last-block final reduction ----
    if (lane == 0) wsum[wave] = lsum;
    __syncthreads();
    if (t == 0) {
        ws[bid0] = wsum[0] + wsum[1] + wsum[2] + wsum[3];
        __threadfence();
        unsigned int old = atomicAdd((unsigned int*)(ws + 2048), 1u);
        s_last = (old == (unsigned int)(NBLK - 1)) ? 1 : 0;
    }
    __syncthreads();
    if (s_last) {
        __threadfence();
        float a = 0.f;
        for (int i = t; i < NBLK; i += NTHR)
            a += __hip_atomic_load(&ws[i], __ATOMIC_ACQUIRE, __HIP_MEMORY_SCOPE_AGENT);
#pragma unroll
        for (int off = 32; off; off >>= 1) a += __shfl_down(a, off, 64);
        if (lane == 0) wsum[wave] = a;
        __syncthreads();
        if (t == 0)
            out[0] = (wsum[0] + wsum[1] + wsum[2] + wsum[3]) * (1.0f / (float)BATCH);
    }
}

extern "C" void kernel_launch(void* const* d_in, const int* in_sizes, int n_in,
                              void* d_out, int out_size, void* d_ws, size_t ws_size,
                              hipStream_t stream) {
    const void* h = d_in[0];
    const void* r = d_in[1];
    const void* pt = d_in[2];
    const void* nt = d_in[3];
    const float* ent = (const float*)d_in[4];
    const float* rel = (const float*)d_in[5];

    // zero the arrival counter (ws word 2048) — capture-legal memset node
    hipMemsetAsync((void*)((char*)d_ws + 2048 * sizeof(float)), 0,
                   sizeof(unsigned int), stream);
    rescal_kernel<<<NBLK, NTHR, 0, stream>>>(h, r, pt, nt, ent, rel,
                                             (float*)d_ws, (float*)d_out);
}

// Round 16
// 61.252 us; speedup vs baseline: 2.0675x; 1.3166x over previous
//
#include <hip/hip_runtime.h>
#include <math.h>

#define BATCH 16384
#define EDIM 128
#define RD (EDIM * EDIM)      // 16384 floats = 64 KB
#define NREL 200
#define SPLIT 4
#define NBLK (NREL * SPLIT)   // 800
#define NTHR 256
#define QUARTER (BATCH / SPLIT)  // 4096
#define NJ (QUARTER / NTHR)      // 16
#define EB 8
#define LISTCAP 256

// ws layout (floats): csum[0 .. NBLK) — per-block partials (plain stores)

__device__ __forceinline__ int load_idx(const void* p, int b, int is64) {
    if (is64) return (int)((const long long*)p)[b];
    return ((const int*)p)[b];
}

__device__ __forceinline__ float bcast_lane(float v, int idx) {
    return __int_as_float(__builtin_amdgcn_readlane(__float_as_int(v), idx));
}

__global__ __launch_bounds__(NTHR) void rescal_kernel(
    const void* __restrict__ hI, const void* __restrict__ rI,
    const void* __restrict__ pI, const void* __restrict__ nI,
    const float* __restrict__ ent, const float* __restrict__ rel,
    float* __restrict__ csum) {
    const int t = threadIdx.x;
    const int bid0 = blockIdx.x;
    // rid-major XCD mapping (R13)
    const int xcd = bid0 & 7;
    const int slot = bid0 >> 3;
    const int rid = xcd + 8 * (slot >> 2);
    const int qtr = slot & 3;
    const int lane = t & 63;
    const int wave = t >> 6;
    const int c2 = lane * 2;

    __shared__ unsigned short list[LISTCAP];
    __shared__ unsigned int wtj[NJ][4];
    __shared__ unsigned int um4[4];
    __shared__ float wsum[4];

    // ---- dtype detect ----
    unsigned int o = ((const unsigned int*)hI)[2 * t + 1] |
                     ((const unsigned int*)rI)[2 * t + 1] |
                     ((const unsigned int*)pI)[2 * t + 1] |
                     ((const unsigned int*)nI)[2 * t + 1];
#pragma unroll
    for (int off = 32; off; off >>= 1) o |= __shfl_xor(o, off, 64);
    if (lane == 0) um4[wave] = o;
    __syncthreads();
    const int is64 = ((um4[0] | um4[1] | um4[2] | um4[3]) == 0u) ? 1 : 0;

    // ---- coalesced ballot scan (R13 verbatim) ----
    const int qbase = qtr * QUARTER;
    unsigned long long bal[NJ];
#pragma unroll
    for (int j = 0; j < NJ; ++j) {
        const int rr = load_idx(rI, qbase + j * NTHR + t, is64);
        bal[j] = __ballot(rr == rid);
        if (lane == 0) wtj[j][wave] = (unsigned int)__popcll(bal[j]);
    }
    __syncthreads();
    int cnt;
    {
        unsigned int run = 0;
        const unsigned long long ltmask = (lane == 63) ? ~0ull >> 1
                                                       : (1ull << lane) - 1ull;
#pragma unroll
        for (int j = 0; j < NJ; ++j) {
            unsigned int wpre = 0, tj = 0;
#pragma unroll
            for (int w = 0; w < 4; ++w) {
                const unsigned int v = wtj[j][w];
                tj += v;
                wpre += (w < wave) ? v : 0;
            }
            if ((bal[j] >> lane) & 1ull) {
                const unsigned int rank =
                    run + wpre + (unsigned int)__popcll(bal[j] & ltmask);
                if (rank < LISTCAP) list[rank] = (unsigned short)(j * NTHR + t);
            }
            run += tj;
        }
        cnt = (int)run;
        if (cnt > LISTCAP) cnt = LISTCAP;
    }
    __syncthreads();  // list complete; no more block syncs until epilogue

    // ---- per-wave independent range ----
    const int per_wave = (cnt + 3) >> 2;
    int lo = wave * per_wave;
    int hi = (wave + 1) * per_wave;
    if (lo > cnt) lo = cnt;
    if (hi > cnt) hi = cnt;

    const float* Rg = rel + (size_t)rid * RD;
    float lsum = 0.f;  // lane-0-of-wave meaningful

    for (int e0 = lo; e0 < hi; e0 += EB) {
        // ---- uniform element handles ----
        int bidx[EB];
        const float* hrow[EB];
#pragma unroll
        for (int i = 0; i < EB; ++i) {
            int e = e0 + i;
            if (e >= hi) e = hi - 1;
            int b = qbase + (int)list[e];
            b = __builtin_amdgcn_readfirstlane(b);
            bidx[i] = b;
            int hix = load_idx(hI, b, is64);
            hix = __builtin_amdgcn_readfirstlane(hix);
            hrow[i] = ent + (size_t)hix * EDIM;
        }

        // ---- h rows into registers: lane l holds h_i[2l], h_i[2l+1] ----
        float2 h2[EB];
#pragma unroll
        for (int i = 0; i < EB; ++i) h2[i] = *(const float2*)(hrow[i] + c2);

        // ---- early tails (HBM misses drain under the d-loop) ----
        float2 tpv[EB], tnv[EB];
#pragma unroll
        for (int i = 0; i < EB; ++i) {
            const int b = bidx[i];
            const int pi = __builtin_amdgcn_readfirstlane(load_idx(pI, b, is64));
            const int ni = __builtin_amdgcn_readfirstlane(load_idx(nI, b, is64));
            tpv[i] = *(const float2*)(ent + (size_t)pi * EDIM + c2);
            tnv[i] = *(const float2*)(ent + (size_t)ni * EDIM + c2);
        }

        // ---- d-loop: ONLY the R load touches memory; h via readlane ----
        float2 acc[EB];
#pragma unroll
        for (int i = 0; i < EB; ++i) acc[i] = make_float2(0.f, 0.f);
        float r2p = 0.f;
#pragma unroll 8
        for (int d = 0; d < EDIM; ++d) {
            const float2 rv = *(const float2*)(Rg + d * EDIM + c2);
            r2p = fmaf(rv.x, rv.x, fmaf(rv.y, rv.y, r2p));
            const int src = d >> 1;       // uniform lane index
#pragma unroll
            for (int i = 0; i < EB; ++i) {
                const float hd = (d & 1) ? bcast_lane(h2[i].y, src)
                                         : bcast_lane(h2[i].x, src);
                acc[i].x = fmaf(rv.x, hd, acc[i].x);
                acc[i].y = fmaf(rv.y, hd, acc[i].y);
            }
        }
#pragma unroll
        for (int off = 32; off; off >>= 1) r2p += __shfl_xor(r2p, off, 64);
        const float r2w = r2p;

        // ---- tails: all operands in registers ----
#pragma unroll
        for (int i = 0; i < EB; ++i) {
            float dp = acc[i].x * tpv[i].x + acc[i].y * tpv[i].y;
            float dn = acc[i].x * tnv[i].x + acc[i].y * tnv[i].y;
            float e2 = h2[i].x * h2[i].x + h2[i].y * h2[i].y +
                       tpv[i].x * tpv[i].x + tpv[i].y * tpv[i].y +
                       tnv[i].x * tnv[i].x + tnv[i].y * tnv[i].y;
#pragma unroll
            for (int off = 32; off; off >>= 1) {
                dp += __shfl_xor(dp, off, 64);
                dn += __shfl_xor(dn, off, 64);
                e2 += __shfl_xor(e2, off, 64);
            }
            if (lane == 0 && (e0 + i) < hi) {
                const float x = dn - dp;  // neg_score - pos_score
                const float spl = (x > 0.f) ? (x + log1pf(expf(-x))) : log1pf(expf(x));
                lsum += spl + 1e-5f * 0.5f * (e2 + r2w);
            }
        }
    }

    // ---- epilogue: plain store of block partial ----
    if (lane == 0) wsum[wave] = lsum;
    __syncthreads();
    if (t == 0) csum[bid0] = wsum[0] + wsum[1] + wsum[2] + wsum[3];
}

__global__ __launch_bounds__(NTHR) void reduce_kernel(const float* __restrict__ csum,
                                                      float* __restrict__ out) {
    const int t = threadIdx.x;
    float a = 0.f;
    for (int i = t; i < NBLK; i += NTHR) a += csum[i];
#pragma unroll
    for (int off = 32; off; off >>= 1) a += __shfl_down(a, off, 64);
    __shared__ float sm[4];
    if ((t & 63) == 0) sm[t >> 6] = a;
    __syncthreads();
    if (t == 0) out[0] = (sm[0] + sm[1] + sm[2] + sm[3]) * (1.0f / (float)BATCH);
}

extern "C" void kernel_launch(void* const* d_in, const int* in_sizes, int n_in,
                              void* d_out, int out_size, void* d_ws, size_t ws_size,
                              hipStream_t stream) {
    const void* h = d_in[0];
    const void* r = d_in[1];
    const void* pt = d_in[2];
    const void* nt = d_in[3];
    const float* ent = (const float*)d_in[4];
    const float* rel = (const float*)d_in[5];
    float* csum = (float*)d_ws;

    rescal_kernel<<<NBLK, NTHR, 0, stream>>>(h, r, pt, nt, ent, rel, csum);
    reduce_kernel<<<1, NTHR, 0, stream>>>(csum, (float*)d_out);
}